// Round 5
// baseline (170.188 us; speedup 1.0000x reference)
//
#include <hip/hip_runtime.h>

#define IN_CH 16
#define OUT_CH 16
#define EDGE_FEAT 32
#define HIDDEN 128
#define WROW 256          // IN_CH*OUT_CH
#define FN_FPB 16         // filters per block in filter-net kernel
#define WSLOTS 64         // per-wave run slots
#define LSTR 16           // LDS floats per slot (16 channels; deg derived)

typedef __fp16 half2_v __attribute__((ext_vector_type(2)));
typedef unsigned uvec4 __attribute__((ext_vector_type(4)));
typedef float fvec4 __attribute__((ext_vector_type(4)));
typedef float fvec2 __attribute__((ext_vector_type(2)));

__device__ __forceinline__ unsigned pk_f16(float lo, float hi) {
  half2_v h = __builtin_amdgcn_cvt_pkrtz(lo, hi);
  return __builtin_bit_cast(unsigned, h);
}

__device__ __forceinline__ float dot2(unsigned wpair, half2_v xp, float acc) {
  half2_v w = __builtin_bit_cast(half2_v, wpair);
#if __has_builtin(__builtin_amdgcn_fdot2)
  return __builtin_amdgcn_fdot2(xp, w, acc, false);
#else
  acc = fmaf((float)xp[0], (float)w[0], acc);
  return fmaf((float)xp[1], (float)w[1], acc);
#endif
}

// ---------------- Kernel 1: filter net (r20: 128B-line quad layout) ---------
// Weight-row layout arranged so the edge kernel fetches 128 B per
// instruction: quad (in-pair u, out-quad jo) lives at 16B-slot
// (u&3)*8 + (u>>2)*4 + jo. Instruction k of an 8-lane edge-slab then reads
// bytes [k*128, k*128+128) and delivers u = 4h+k to lane (h, j).
__global__ __launch_bounds__(256) void filter_net_kernel(
    const float* __restrict__ ef, const float* __restrict__ W1,
    const float* __restrict__ b1, const float* __restrict__ W2,
    const float* __restrict__ b2, unsigned short* __restrict__ weights,
    float* __restrict__ zero_base, int nzero4) {
  const int t = threadIdx.x;
  const int f0 = blockIdx.x * FN_FPB;

  for (int gid = blockIdx.x * 256 + t; gid < nzero4; gid += gridDim.x * 256)
    ((float4*)zero_base)[gid] = make_float4(0.f, 0.f, 0.f, 0.f);

  __shared__ float ef_s[FN_FPB * EDGE_FEAT];   // 2 KB
  __shared__ float h_s[FN_FPB][HIDDEN];        // 8 KB
  ef_s[t] = ef[f0 * EDGE_FEAT + t];
  ef_s[t + 256] = ef[f0 * EDGE_FEAT + t + 256];
  __syncthreads();

  // stage 1: 2048 h values, 8 per thread.
  {
    const int hi = t & 127;
    const int fb = (t >> 7) * 8;
    float a[8];
    #pragma unroll
    for (int r = 0; r < 8; ++r) a[r] = b1[hi];
    for (int k0 = 0; k0 < EDGE_FEAT; k0 += 4) {
      float w1v[4];
      #pragma unroll
      for (int m = 0; m < 4; ++m) w1v[m] = W1[(k0 + m) * HIDDEN + hi];
      #pragma unroll
      for (int r = 0; r < 8; ++r) {
        const float4 e4 = *(const float4*)&ef_s[(fb + r) * EDGE_FEAT + k0];
        a[r] = fmaf(e4.x, w1v[0], a[r]);
        a[r] = fmaf(e4.y, w1v[1], a[r]);
        a[r] = fmaf(e4.z, w1v[2], a[r]);
        a[r] = fmaf(e4.w, w1v[3], a[r]);
      }
    }
    #pragma unroll
    for (int r = 0; r < 8; ++r) h_s[fb + r][hi] = a[r] > 0.f ? a[r] : 0.f;
  }
  __syncthreads();

  // stage 2: cq owns cols 4cq..4cq+3 for filters grp*4..grp*4+3.
  const int cq = t & 63;
  const int grp = t >> 6;
  float4 facc[4];
  const float4 bb = *(const float4*)(b2 + 4 * cq);
  #pragma unroll
  for (int q = 0; q < 4; ++q) facc[q] = bb;
  for (int k0 = 0; k0 < HIDDEN; k0 += 4) {
    float4 w2v[4];
    #pragma unroll
    for (int m = 0; m < 4; ++m)
      w2v[m] = ((const float4*)(W2 + (size_t)(k0 + m) * WROW))[cq];
    #pragma unroll
    for (int q = 0; q < 4; ++q) {
      const float4 h4 = *(const float4*)&h_s[grp * 4 + q][k0];
      facc[q].x = fmaf(h4.x, w2v[0].x, facc[q].x);
      facc[q].y = fmaf(h4.x, w2v[0].y, facc[q].y);
      facc[q].z = fmaf(h4.x, w2v[0].z, facc[q].z);
      facc[q].w = fmaf(h4.x, w2v[0].w, facc[q].w);
      facc[q].x = fmaf(h4.y, w2v[1].x, facc[q].x);
      facc[q].y = fmaf(h4.y, w2v[1].y, facc[q].y);
      facc[q].z = fmaf(h4.y, w2v[1].z, facc[q].z);
      facc[q].w = fmaf(h4.y, w2v[1].w, facc[q].w);
      facc[q].x = fmaf(h4.z, w2v[2].x, facc[q].x);
      facc[q].y = fmaf(h4.z, w2v[2].y, facc[q].y);
      facc[q].z = fmaf(h4.z, w2v[2].z, facc[q].z);
      facc[q].w = fmaf(h4.z, w2v[2].w, facc[q].w);
      facc[q].x = fmaf(h4.w, w2v[3].x, facc[q].x);
      facc[q].y = fmaf(h4.w, w2v[3].y, facc[q].y);
      facc[q].z = fmaf(h4.w, w2v[3].z, facc[q].z);
      facc[q].w = fmaf(h4.w, w2v[3].w, facc[q].w);
    }
  }

  const int i = cq >> 2;
  const int jo = cq & 3;
  const int u = i >> 1;
  #pragma unroll
  for (int q = 0; q < 4; ++q) {
    float4 oth;
    oth.x = __shfl_xor(facc[q].x, 4);
    oth.y = __shfl_xor(facc[q].y, 4);
    oth.z = __shfl_xor(facc[q].z, 4);
    oth.w = __shfl_xor(facc[q].w, 4);
    if ((i & 1) == 0) {
      uint4 st;
      st.x = pk_f16(facc[q].x, oth.x);
      st.y = pk_f16(facc[q].y, oth.y);
      st.z = pk_f16(facc[q].z, oth.z);
      st.w = pk_f16(facc[q].w, oth.w);
      // r20 layout: quad (u, jo) -> 16B slot ((u&3)*8 + (u>>2)*4 + jo)
      *(uint4*)(weights + (size_t)(f0 + grp * 4 + q) * WROW +
                (((u & 3) * 8 + (u >> 2) * 4 + jo)) * 8) = st;
    }
  }
}

// ---------------- Kernel 2: edge kernel r21 — 128B requests, DPP fixed ------
// r20 post-mortem: failed correctness. DPP convention on this HW (proven by
// r15's verified comments): row_shl:N reads lane l+N, row_shr:N reads lane
// l-N. r20's seg-merge was accidentally a correct BACKWARD scan (absorb
// next edge via 0x108, write at run head via 0x118 prev-slot check), but the
// half-merge used 0x114 (= lane l-4 = WRONG edge's upper half). Fix: 0x104.
// Everything else unchanged: 8 lanes/edge, each weight instr = one 128 B
// line (4 weight requests/edge vs 8), x as dwordx2; asm-forced loads,
// depth-3 rotation, counted vmcnt (never 0 mid-loop).
template <int CTRL, int OLD>
__device__ __forceinline__ int dpp_i(int v) {
  return __builtin_amdgcn_update_dpp(OLD, v, CTRL, 0xf, 0xf, false);
}
template <int CTRL>
__device__ __forceinline__ float dpp_f(float v) {
  return __builtin_bit_cast(
      float, __builtin_amdgcn_update_dpp(0, __builtin_bit_cast(int, v), CTRL,
                                         0xf, 0xf, false));
}
template <int Q>
__device__ __forceinline__ int quad_bcast_dpp(int v) {
  return __builtin_amdgcn_update_dpp(0, v, Q * 0x55, 0xf, 0xf, false);
}

template <int IOFF>
__device__ __forceinline__ uvec4 ldw16(const unsigned short* base,
                                       unsigned voff) {
  uvec4 r;
  asm volatile("global_load_dwordx4 %0, %1, %2 offset:%3"
               : "=v"(r)
               : "v"(voff), "s"(base), "i"(IOFF));
  return r;
}

__device__ __forceinline__ fvec2 ldxf2(const float* base, unsigned voff) {
  fvec2 r;
  asm volatile("global_load_dwordx2 %0, %1, %2"
               : "=v"(r)
               : "v"(voff), "s"(base));
  return r;
}

#define ISSUE_G8(g, wv, xo)                     \
  do {                                          \
    xo = ldxf2(input, xoff8[g]);                \
    wv[0] = ldw16<0>(weights, woff8[g]);        \
    wv[1] = ldw16<128>(weights, woff8[g]);      \
    wv[2] = ldw16<256>(weights, woff8[g]);      \
    wv[3] = ldw16<384>(weights, woff8[g]);      \
  } while (0)

#define VMWAIT(N)                                          \
  asm volatile("s_waitcnt vmcnt(" #N ")" ::: "memory");    \
  __builtin_amdgcn_sched_barrier(0)

// One 8-edge phase. Lane l: oct=l>>3 (edge), h=(l>>2)&1 (in-half), j=l&3
// (out-quad). wv[k] = weight quad (u=4h+k, j); xo = own x-pair (pos=l&7).
__device__ __forceinline__ void do_phase8(const fvec2 xo, const uvec4* wv,
                                          const int sl, const bool ve,
                                          const bool hlow, const int j,
                                          float* __restrict__ acc_w) {
  const int p = (int)pk_f16(xo.x, xo.y);
  half2_v xp[4];
  xp[0] = __builtin_bit_cast(half2_v, quad_bcast_dpp<0>(p));
  xp[1] = __builtin_bit_cast(half2_v, quad_bcast_dpp<1>(p));
  xp[2] = __builtin_bit_cast(half2_v, quad_bcast_dpp<2>(p));
  xp[3] = __builtin_bit_cast(half2_v, quad_bcast_dpp<3>(p));

  fvec4 acc = {0.f, 0.f, 0.f, 0.f};
  #pragma unroll
  for (int k = 0; k < 4; ++k) {
    acc.x = dot2(wv[k].x, xp[k], acc.x);
    acc.y = dot2(wv[k].y, xp[k], acc.y);
    acc.z = dot2(wv[k].z, xp[k], acc.z);
    acc.w = dot2(wv[k].w, xp[k], acc.w);
  }
  if (!ve) { acc.x = 0.f; acc.y = 0.f; acc.z = 0.f; acc.w = 0.f; }

  // half-merge: h=0 lanes absorb own edge's h=1 partial (lane l+4 ->
  // row_shl:4 = 0x104 on this HW; r20's 0x114 read lane l-4 = WRONG edge).
  acc.x += dpp_f<0x104>(acc.x);
  acc.y += dpp_f<0x104>(acc.y);
  acc.z += dpp_f<0x104>(acc.z);
  acc.w += dpp_f<0x104>(acc.w);

  // backward seg merge: absorb NEXT edge (lane l+8, row_shl:8) if same slot.
  {
    const int os = dpp_i<0x108, -1>(sl);
    const float ox = dpp_f<0x108>(acc.x);
    const float oy = dpp_f<0x108>(acc.y);
    const float oz = dpp_f<0x108>(acc.z);
    const float ow = dpp_f<0x108>(acc.w);
    if (os == sl) { acc.x += ox; acc.y += oy; acc.z += oz; acc.w += ow; }
  }
  // run-head write: prev edge (lane l-8, row_shr:8) has a different slot.
  const int pslot = dpp_i<0x118, -1>(sl);
  if (ve && hlow && pslot != sl) {
    float* p4 = acc_w + sl * LSTR + j * 4;
    atomicAdd(p4 + 0, acc.x);
    atomicAdd(p4 + 1, acc.y);
    atomicAdd(p4 + 2, acc.z);
    atomicAdd(p4 + 3, acc.w);
  }
}

__global__ __launch_bounds__(256, 4) void edge_kernel(
    const float* __restrict__ input, const int* __restrict__ idxn,
    const int* __restrict__ idxe, const int* __restrict__ seg,
    const unsigned short* __restrict__ weights, float* __restrict__ sums,
    float* __restrict__ deg, int n_edges) {
  __shared__ float lds_acc[4][WSLOTS * LSTR];   // 4 x 4 KB (wave-private)
  __shared__ int lds_map[4][WSLOTS];

  const int t = threadIdx.x;
  const int lane = t & 63;
  const int w = t >> 6;
  const int oct = lane >> 3;
  const int pos = lane & 7;
  const bool hlow = (lane & 4) == 0;
  const int j = lane & 3;
  float* __restrict__ acc_w = lds_acc[w];

  const long wv_base = (long)blockIdx.x * 256 + w * 64;
  long rem = n_edges - wv_base;
  const int valid_cnt = rem < 0 ? 0 : (rem > 64 ? 64 : (int)rem);

  long el = wv_base + lane;
  const bool vl = el < n_edges;
  if (!vl) el = n_edges - 1;
  const int s_l = seg[el];
  const int n_l = idxn[el];
  const int f_l = idxe[el];
  const int sv = vl ? s_l : -1;

  // ---- bookkeeping FIRST: all compiler-issued vmem (seg/idxn/idxe) is
  // consumed here, before the asm-load region, so hw vmcnt is ours alone.
  const int sprev = __shfl(sv, (lane - 1) & 63);
  const bool head = vl && (lane == 0 || sprev != sv);
  const unsigned long long bal = __ballot(head);
  const int r = (int)__popcll(bal & ((1ull << lane) - 1ull));
  const int r_w = (int)__popcll(bal);

  for (int idx = lane; idx < r_w * LSTR; idx += 64) acc_w[idx] = 0.f;

  const int slot_l = r - (head ? 0 : 1);
  if (head) lds_map[w][slot_l] = (lane << 20) | sv;   // head lane | node id

  int slv8[8];
  unsigned woff8[8], xoff8[8];
  #pragma unroll
  for (int g = 0; g < 8; ++g) {
    const int src = g * 8 + oct;
    const int fg = __shfl(f_l, src);
    const int ng = __shfl(n_l, src);
    slv8[g] = __shfl(slot_l, src);
    woff8[g] = ((unsigned)fg << 9) | (pos << 4);
    xoff8[g] = ((unsigned)ng << 6) | (pos << 3);
  }

  // ---- asm-load region: depth-3 rotation, 5 loads/group, counted waits.
  uvec4 wvA[4], wvB[4], wvC[4];
  fvec2 xoA, xoB, xoC;
  ISSUE_G8(0, wvA, xoA);                   //  5 in flight
  ISSUE_G8(1, wvB, xoB);                   // 10
  ISSUE_G8(2, wvC, xoC);                   // 15

  VMWAIT(10);  // g0 ready
  do_phase8(xoA, wvA, slv8[0], 0 + oct < valid_cnt, hlow, j, acc_w);
  ISSUE_G8(3, wvA, xoA);
  VMWAIT(10);  // g1 ready
  do_phase8(xoB, wvB, slv8[1], 8 + oct < valid_cnt, hlow, j, acc_w);
  ISSUE_G8(4, wvB, xoB);
  VMWAIT(10);  // g2 ready
  do_phase8(xoC, wvC, slv8[2], 16 + oct < valid_cnt, hlow, j, acc_w);
  ISSUE_G8(5, wvC, xoC);
  VMWAIT(10);  // g3 ready
  do_phase8(xoA, wvA, slv8[3], 24 + oct < valid_cnt, hlow, j, acc_w);
  ISSUE_G8(6, wvA, xoA);
  VMWAIT(10);  // g4 ready
  do_phase8(xoB, wvB, slv8[4], 32 + oct < valid_cnt, hlow, j, acc_w);
  ISSUE_G8(7, wvB, xoB);
  VMWAIT(10);  // g5 ready
  do_phase8(xoC, wvC, slv8[5], 40 + oct < valid_cnt, hlow, j, acc_w);
  VMWAIT(5);   // g6 ready
  do_phase8(xoA, wvA, slv8[6], 48 + oct < valid_cnt, hlow, j, acc_w);
  VMWAIT(0);   // g7 ready (pipeline drained)
  do_phase8(xoB, wvB, slv8[7], 56 + oct < valid_cnt, hlow, j, acc_w);

  // drain wave-local DS before reading slots (no barrier: wave-private).
  asm volatile("s_waitcnt lgkmcnt(0)" ::: "memory");

  // flush; deg derived from head-lane deltas (no cnt accumulation).
  const int ch = lane & 15;
  for (int slot = lane >> 4; slot < r_w; slot += 4) {
    const int m0 = lds_map[w][slot];
    const int node = m0 & 0xFFFFF;
    atomicAdd(sums + ((size_t)node << 4) + ch, acc_w[slot * LSTR + ch]);
    if (ch == 0) {
      const int start = m0 >> 20;
      const int end =
          (slot + 1 < r_w) ? (lds_map[w][slot + 1] >> 20) : valid_cnt;
      atomicAdd(deg + node, (float)(end - start));
    }
  }
}

// ---------------- Kernel 3: divide by degree --------------------------------
__global__ __launch_bounds__(256) void finalize_kernel(
    const float* __restrict__ sums, const float* __restrict__ deg,
    float* __restrict__ out, int n_nodes) {
  const int n = blockIdx.x * blockDim.x + threadIdx.x;
  if (n >= n_nodes) return;
  const float d = deg[n];
  const float scale = d > 0.f ? 1.f / d : 0.f;
  const float4* sp = (const float4*)(sums + (size_t)n * OUT_CH);
  float4* op = (float4*)(out + (size_t)n * OUT_CH);
  #pragma unroll
  for (int q = 0; q < 4; ++q) {
    float4 v = sp[q];
    v.x *= scale; v.y *= scale; v.z *= scale; v.w *= scale;
    op[q] = v;
  }
}

extern "C" void kernel_launch(void* const* d_in, const int* in_sizes, int n_in,
                              void* d_out, int out_size, void* d_ws, size_t ws_size,
                              hipStream_t stream) {
  const float* input = (const float*)d_in[0];
  const int* idxn    = (const int*)d_in[1];
  const int* idxe    = (const int*)d_in[2];
  const int* seg     = (const int*)d_in[3];
  const float* ef    = (const float*)d_in[4];
  const float* W1    = (const float*)d_in[5];
  const float* b1    = (const float*)d_in[6];
  const float* W2    = (const float*)d_in[7];
  const float* b2    = (const float*)d_in[8];
  float* out = (float*)d_out;

  const int n_nodes   = in_sizes[0] / IN_CH;
  const int n_edges   = in_sizes[1];
  const int n_filters = in_sizes[4] / EDGE_FEAT;

  // workspace: f16 weights [F*256] (2 MB) | sums [n_nodes*16] | deg [n_nodes]
  unsigned short* weights = (unsigned short*)d_ws;
  float* sums = (float*)((char*)d_ws + (size_t)n_filters * WROW * sizeof(unsigned short));
  float* deg  = sums + (size_t)n_nodes * OUT_CH;

  const int nzero4 = (n_nodes * (OUT_CH + 1)) / 4;
  filter_net_kernel<<<n_filters / FN_FPB, 256, 0, stream>>>(
      ef, W1, b1, W2, b2, weights, sums, nzero4);

  const long n_blocks = ((long)n_edges + 255) / 256;
  edge_kernel<<<(int)n_blocks, 256, 0, stream>>>(
      input, idxn, idxe, seg, weights, sums, deg, n_edges);

  finalize_kernel<<<(n_nodes + 255) / 256, 256, 0, stream>>>(sums, deg, out,
                                                             n_nodes);
}

// Round 6
// 149.340 us; speedup vs baseline: 1.1396x; 1.1396x over previous
//
#include <hip/hip_runtime.h>

#define IN_CH 16
#define OUT_CH 16
#define EDGE_FEAT 32
#define HIDDEN 128
#define WROW 256          // IN_CH*OUT_CH
#define FN_FPB 16         // filters per block in filter-net kernel
#define WSLOTS 64         // per-wave run slots
#define LSTR 16           // LDS floats per slot (16 channels; deg derived)
#define ECHUNK 4          // 256-edge chunks per block (r22: dispatch-rate fix)

typedef __fp16 half2_v __attribute__((ext_vector_type(2)));
typedef unsigned uvec4 __attribute__((ext_vector_type(4)));
typedef float fvec4 __attribute__((ext_vector_type(4)));

__device__ __forceinline__ unsigned pk_f16(float lo, float hi) {
  half2_v h = __builtin_amdgcn_cvt_pkrtz(lo, hi);
  return __builtin_bit_cast(unsigned, h);
}

__device__ __forceinline__ float dot2(unsigned wpair, half2_v xp, float acc) {
  half2_v w = __builtin_bit_cast(half2_v, wpair);
#if __has_builtin(__builtin_amdgcn_fdot2)
  return __builtin_amdgcn_fdot2(xp, w, acc, false);
#else
  acc = fmaf((float)xp[0], (float)w[0], acc);
  return fmaf((float)xp[1], (float)w[1], acc);
#endif
}

// ---------------- Kernel 1: filter net v2 (r14, measured -7 µs) -------------
__global__ __launch_bounds__(256) void filter_net_kernel(
    const float* __restrict__ ef, const float* __restrict__ W1,
    const float* __restrict__ b1, const float* __restrict__ W2,
    const float* __restrict__ b2, unsigned short* __restrict__ weights,
    float* __restrict__ zero_base, int nzero4) {
  const int t = threadIdx.x;
  const int f0 = blockIdx.x * FN_FPB;

  for (int gid = blockIdx.x * 256 + t; gid < nzero4; gid += gridDim.x * 256)
    ((float4*)zero_base)[gid] = make_float4(0.f, 0.f, 0.f, 0.f);

  __shared__ float ef_s[FN_FPB * EDGE_FEAT];   // 2 KB
  __shared__ float h_s[FN_FPB][HIDDEN];        // 8 KB
  ef_s[t] = ef[f0 * EDGE_FEAT + t];
  ef_s[t + 256] = ef[f0 * EDGE_FEAT + t + 256];
  __syncthreads();

  // stage 1: 2048 h values, 8 per thread.
  {
    const int hi = t & 127;
    const int fb = (t >> 7) * 8;
    float a[8];
    #pragma unroll
    for (int r = 0; r < 8; ++r) a[r] = b1[hi];
    for (int k0 = 0; k0 < EDGE_FEAT; k0 += 4) {
      float w1v[4];
      #pragma unroll
      for (int m = 0; m < 4; ++m) w1v[m] = W1[(k0 + m) * HIDDEN + hi];
      #pragma unroll
      for (int r = 0; r < 8; ++r) {
        const float4 e4 = *(const float4*)&ef_s[(fb + r) * EDGE_FEAT + k0];
        a[r] = fmaf(e4.x, w1v[0], a[r]);
        a[r] = fmaf(e4.y, w1v[1], a[r]);
        a[r] = fmaf(e4.z, w1v[2], a[r]);
        a[r] = fmaf(e4.w, w1v[3], a[r]);
      }
    }
    #pragma unroll
    for (int r = 0; r < 8; ++r) h_s[fb + r][hi] = a[r] > 0.f ? a[r] : 0.f;
  }
  __syncthreads();

  // stage 2: cq owns cols 4cq..4cq+3 for filters grp*4..grp*4+3.
  const int cq = t & 63;
  const int grp = t >> 6;
  float4 facc[4];
  const float4 bb = *(const float4*)(b2 + 4 * cq);
  #pragma unroll
  for (int q = 0; q < 4; ++q) facc[q] = bb;
  for (int k0 = 0; k0 < HIDDEN; k0 += 4) {
    float4 w2v[4];
    #pragma unroll
    for (int m = 0; m < 4; ++m)
      w2v[m] = ((const float4*)(W2 + (size_t)(k0 + m) * WROW))[cq];
    #pragma unroll
    for (int q = 0; q < 4; ++q) {
      const float4 h4 = *(const float4*)&h_s[grp * 4 + q][k0];
      facc[q].x = fmaf(h4.x, w2v[0].x, facc[q].x);
      facc[q].y = fmaf(h4.x, w2v[0].y, facc[q].y);
      facc[q].z = fmaf(h4.x, w2v[0].z, facc[q].z);
      facc[q].w = fmaf(h4.x, w2v[0].w, facc[q].w);
      facc[q].x = fmaf(h4.y, w2v[1].x, facc[q].x);
      facc[q].y = fmaf(h4.y, w2v[1].y, facc[q].y);
      facc[q].z = fmaf(h4.y, w2v[1].z, facc[q].z);
      facc[q].w = fmaf(h4.y, w2v[1].w, facc[q].w);
      facc[q].x = fmaf(h4.z, w2v[2].x, facc[q].x);
      facc[q].y = fmaf(h4.z, w2v[2].y, facc[q].y);
      facc[q].z = fmaf(h4.z, w2v[2].z, facc[q].z);
      facc[q].w = fmaf(h4.z, w2v[2].w, facc[q].w);
      facc[q].x = fmaf(h4.w, w2v[3].x, facc[q].x);
      facc[q].y = fmaf(h4.w, w2v[3].y, facc[q].y);
      facc[q].z = fmaf(h4.w, w2v[3].z, facc[q].z);
      facc[q].w = fmaf(h4.w, w2v[3].w, facc[q].w);
    }
  }

  const int i = cq >> 2;
  const int jo = cq & 3;
  const int u = i >> 1;
  #pragma unroll
  for (int q = 0; q < 4; ++q) {
    float4 oth;
    oth.x = __shfl_xor(facc[q].x, 4);
    oth.y = __shfl_xor(facc[q].y, 4);
    oth.z = __shfl_xor(facc[q].z, 4);
    oth.w = __shfl_xor(facc[q].w, 4);
    if ((i & 1) == 0) {
      uint4 st;
      st.x = pk_f16(facc[q].x, oth.x);
      st.y = pk_f16(facc[q].y, oth.y);
      st.z = pk_f16(facc[q].z, oth.z);
      st.w = pk_f16(facc[q].w, oth.w);
      *(uint4*)(weights + (size_t)(f0 + grp * 4 + q) * WROW +
                (u * 4 + jo) * 8) = st;
    }
  }
}

// ---------------- Kernel 2: edge kernel r22 — r15 body + chunk loop ---------
// r17-r21 post-mortems: reg-prefetch (sunk by allocator), LDS-DMA (occupancy
// collapse), asm depth-2 (flat), asm depth-3/128B (spills; and 64B-line
// count was identical anyway) — all >= r15's 51.5 µs. Every memory pipe
// sits at ~50% and MLP doesn't move it. Remaining unexplained counter:
// OccupancyPercent=58% with nothing statically capping below 100% -> block
// dispatch-rate / ramp limit (6250 x ~2 µs blocks need ~121 starts/µs).
// r22: identical r15 per-chunk body; each block processes ECHUNK=4
// consecutive 256-edge chunks (grid 6250 -> 1563) to quarter the dispatch
// rate and amortize block start/stop. No other changes.
template <int CTRL, int OLD>
__device__ __forceinline__ int dpp_i(int v) {
  return __builtin_amdgcn_update_dpp(OLD, v, CTRL, 0xf, 0xf, false);
}
template <int CTRL>
__device__ __forceinline__ float dpp_f(float v) {
  return __builtin_bit_cast(
      float, __builtin_amdgcn_update_dpp(0, __builtin_bit_cast(int, v), CTRL,
                                         0xf, 0xf, false));
}
template <int Q>
__device__ __forceinline__ int quad_bcast_dpp(int v) {
  return __builtin_amdgcn_update_dpp(0, v, Q * 0x55, 0xf, 0xf, false);
}

template <int CTRL>
__device__ __forceinline__ void seg_step_dpp(int sl, fvec4& acc) {
  const int os = dpp_i<CTRL, -1>(sl);
  const float ox = dpp_f<CTRL>(acc.x);
  const float oy = dpp_f<CTRL>(acc.y);
  const float oz = dpp_f<CTRL>(acc.z);
  const float ow = dpp_f<CTRL>(acc.w);
  if (os == sl) {
    acc.x += ox; acc.y += oy; acc.z += oz; acc.w += ow;
  }
}

__device__ __forceinline__ fvec4 edge_dot(const fvec4 xo, const uvec4* wv) {
  const int p0 = (int)pk_f16(xo.x, xo.y);
  const int p1 = (int)pk_f16(xo.z, xo.w);
  half2_v xp[8];
  xp[0] = __builtin_bit_cast(half2_v, quad_bcast_dpp<0>(p0));
  xp[1] = __builtin_bit_cast(half2_v, quad_bcast_dpp<0>(p1));
  xp[2] = __builtin_bit_cast(half2_v, quad_bcast_dpp<1>(p0));
  xp[3] = __builtin_bit_cast(half2_v, quad_bcast_dpp<1>(p1));
  xp[4] = __builtin_bit_cast(half2_v, quad_bcast_dpp<2>(p0));
  xp[5] = __builtin_bit_cast(half2_v, quad_bcast_dpp<2>(p1));
  xp[6] = __builtin_bit_cast(half2_v, quad_bcast_dpp<3>(p0));
  xp[7] = __builtin_bit_cast(half2_v, quad_bcast_dpp<3>(p1));

  fvec4 acc = {0.f, 0.f, 0.f, 0.f};
  #pragma unroll
  for (int u = 0; u < 8; ++u) {
    acc.x = dot2(wv[u].x, xp[u], acc.x);
    acc.y = dot2(wv[u].y, xp[u], acc.y);
    acc.z = dot2(wv[u].z, xp[u], acc.z);
    acc.w = dot2(wv[u].w, xp[u], acc.w);
  }
  return acc;
}

__global__ __launch_bounds__(256) void edge_kernel(
    const float* __restrict__ input, const int* __restrict__ idxn,
    const int* __restrict__ idxe, const int* __restrict__ seg,
    const unsigned short* __restrict__ weights, float* __restrict__ sums,
    float* __restrict__ deg, int n_edges) {
  __shared__ float lds_acc[4][WSLOTS * LSTR];   // 4 x 4 KB (wave-private)
  __shared__ int lds_map[4][WSLOTS];

  const int t = threadIdx.x;
  const int lane = t & 63;
  const int w = t >> 6;
  const int e16 = lane >> 2;
  const int j = lane & 3;
  float* __restrict__ acc_w = lds_acc[w];

  for (int c = 0; c < ECHUNK; ++c) {
    const long wv_base =
        ((long)blockIdx.x * ECHUNK + c) * 256 + w * 64;
    if (wv_base >= n_edges) break;     // wave-uniform; no barriers in kernel
    long rem = n_edges - wv_base;
    const int valid_cnt = rem > 64 ? 64 : (int)rem;

    long el = wv_base + lane;
    const bool vl = el < n_edges;
    if (!vl) el = n_edges - 1;
    const int s_l = seg[el];
    const int n_l = idxn[el];
    const int f_l = idxe[el];
    const int sv = vl ? s_l : -1;

    const int sprev = __shfl(sv, (lane - 1) & 63);
    const bool head = vl && (lane == 0 || sprev != sv);
    const unsigned long long bal = __ballot(head);
    const int r = (int)__popcll(bal & ((1ull << lane) - 1ull));
    const int r_w = (int)__popcll(bal);

    for (int idx = lane; idx < r_w * LSTR; idx += 64) acc_w[idx] = 0.f;

    const int slot_l = r - (head ? 0 : 1);
    if (head) lds_map[w][slot_l] = (lane << 20) | sv;  // head lane | node id

    // 4 phases of 16 edges; relaxed scheduling (the compiler's interleave
    // beat every source-pinned pipeline attempted in r9..r21).
    #pragma unroll
    for (int g = 0; g < 4; ++g) {
      const int src = g * 16 + e16;
      const int fg = __shfl(f_l, src);
      const int ng = __shfl(n_l, src);
      const int sl = __shfl(slot_l, src);
      const bool ve = src < valid_cnt;

      const char* __restrict__ wb =
          (const char*)weights + (((size_t)fg << 9) | (j << 4));
      uvec4 wv[8];
      #pragma unroll
      for (int u = 0; u < 8; ++u) wv[u] = *(const uvec4*)(wb + (u << 6));
      const fvec4 xo = *(const fvec4*)(input + ((size_t)ng << 4) + (j << 2));

      fvec4 acc = edge_dot(xo, wv);
      if (!ve) { acc.x = 0.f; acc.y = 0.f; acc.z = 0.f; acc.w = 0.f; }

      seg_step_dpp<0x104>(sl, acc);            // + next edge (within row)
      seg_step_dpp<0x108>(sl, acc);            // + edges +2,+3
      const int pslot = dpp_i<0x114, -1>(sl);  // prev edge's slot
      if (ve && pslot != sl) {                 // sub-run head -> LDS accum
        float* p = acc_w + sl * LSTR + j * 4;
        atomicAdd(p + 0, acc.x);
        atomicAdd(p + 1, acc.y);
        atomicAdd(p + 2, acc.z);
        atomicAdd(p + 3, acc.w);
      }
    }

    // drain wave-local DS before reading slots (no barrier: wave-private).
    asm volatile("s_waitcnt lgkmcnt(0)" ::: "memory");

    // flush; deg derived from head-lane deltas (no cnt accumulation).
    const int ch = lane & 15;
    for (int slot = lane >> 4; slot < r_w; slot += 4) {
      const int m0 = lds_map[w][slot];
      const int node = m0 & 0xFFFFF;
      atomicAdd(sums + ((size_t)node << 4) + ch, acc_w[slot * LSTR + ch]);
      if (ch == 0) {
        const int start = m0 >> 20;
        const int end =
            (slot + 1 < r_w) ? (lds_map[w][slot + 1] >> 20) : valid_cnt;
        atomicAdd(deg + node, (float)(end - start));
      }
    }
    // next chunk's zero-writes can't pass the flush's ds_reads: the read
    // values are consumed through VGPRs (hw enforces the dependency).
  }
}

// ---------------- Kernel 3: divide by degree --------------------------------
__global__ __launch_bounds__(256) void finalize_kernel(
    const float* __restrict__ sums, const float* __restrict__ deg,
    float* __restrict__ out, int n_nodes) {
  const int n = blockIdx.x * blockDim.x + threadIdx.x;
  if (n >= n_nodes) return;
  const float d = deg[n];
  const float scale = d > 0.f ? 1.f / d : 0.f;
  const float4* sp = (const float4*)(sums + (size_t)n * OUT_CH);
  float4* op = (float4*)(out + (size_t)n * OUT_CH);
  #pragma unroll
  for (int q = 0; q < 4; ++q) {
    float4 v = sp[q];
    v.x *= scale; v.y *= scale; v.z *= scale; v.w *= scale;
    op[q] = v;
  }
}

extern "C" void kernel_launch(void* const* d_in, const int* in_sizes, int n_in,
                              void* d_out, int out_size, void* d_ws, size_t ws_size,
                              hipStream_t stream) {
  const float* input = (const float*)d_in[0];
  const int* idxn    = (const int*)d_in[1];
  const int* idxe    = (const int*)d_in[2];
  const int* seg     = (const int*)d_in[3];
  const float* ef    = (const float*)d_in[4];
  const float* W1    = (const float*)d_in[5];
  const float* b1    = (const float*)d_in[6];
  const float* W2    = (const float*)d_in[7];
  const float* b2    = (const float*)d_in[8];
  float* out = (float*)d_out;

  const int n_nodes   = in_sizes[0] / IN_CH;
  const int n_edges   = in_sizes[1];
  const int n_filters = in_sizes[4] / EDGE_FEAT;

  // workspace: f16 weights [F*256] (2 MB) | sums [n_nodes*16] | deg [n_nodes]
  unsigned short* weights = (unsigned short*)d_ws;
  float* sums = (float*)((char*)d_ws + (size_t)n_filters * WROW * sizeof(unsigned short));
  float* deg  = sums + (size_t)n_nodes * OUT_CH;

  const int nzero4 = (n_nodes * (OUT_CH + 1)) / 4;
  filter_net_kernel<<<n_filters / FN_FPB, 256, 0, stream>>>(
      ef, W1, b1, W2, b2, weights, sums, nzero4);

  const long n_blocks = ((long)n_edges + 256L * ECHUNK - 1) / (256L * ECHUNK);
  edge_kernel<<<(int)n_blocks, 256, 0, stream>>>(
      input, idxn, idxe, seg, weights, sums, deg, n_edges);

  finalize_kernel<<<(n_nodes + 255) / 256, 256, 0, stream>>>(sums, deg, out,
                                                             n_nodes);
}

// Round 7
// 139.917 us; speedup vs baseline: 1.2163x; 1.0673x over previous
//
#include <hip/hip_runtime.h>

#define IN_CH 16
#define OUT_CH 16
#define EDGE_FEAT 32
#define HIDDEN 128
#define WROW 256          // IN_CH*OUT_CH
#define FN_FPB 16         // filters per block in filter-net kernel
#define WSLOTS 64         // per-wave run slots
#define LSTR 16           // LDS floats per slot (16 channels; deg derived)

typedef __fp16 half2_v __attribute__((ext_vector_type(2)));
typedef unsigned uvec4 __attribute__((ext_vector_type(4)));
typedef float fvec4 __attribute__((ext_vector_type(4)));

__device__ __forceinline__ unsigned pk_f16(float lo, float hi) {
  half2_v h = __builtin_amdgcn_cvt_pkrtz(lo, hi);
  return __builtin_bit_cast(unsigned, h);
}

// int8 dot4: c += sum a.i8[k]*b.i8[k]  (V_DOT4_I32_I8)
__device__ __forceinline__ int dot4i8(unsigned a, unsigned b, int c) {
#if __has_builtin(__builtin_amdgcn_sdot4)
  return __builtin_amdgcn_sdot4((int)a, (int)b, c, false);
#else
  c += (int)(signed char)(a) * (int)(signed char)(b);
  c += (int)(signed char)(a >> 8) * (int)(signed char)(b >> 8);
  c += (int)(signed char)(a >> 16) * (int)(signed char)(b >> 16);
  c += (int)(signed char)(a >> 24) * (int)(signed char)(b >> 24);
  return c;
#endif
}

__device__ __forceinline__ unsigned q8(float v, float inv) {
  return (unsigned)(((int)rintf(v * inv)) & 0xFF);
}

// ---------------- Kernel 1: filter net r23 — int8 rows + scales -------------
// r17-r22: every scheduling/layout variant of the f16 edge gather >= 51.5 µs;
// all pipes ~50%. Line-count is layout-invariant (512 64B lines per 64-edge
// wave) -> only BYTE reduction moves the wall. r23 quantizes weights to int8
// with a per-filter scale (wave-allreduce max) and x to int8 with a per-node
// scale; edge dot becomes v_dot4_i32_i8. 280 B/edge vs 576 B (2.1x).
// Weight row layout (64 dwords): dword p = k*16 + c holds bytes
// w[4k+kk][c], kk=0..3  (k = input-quad, c = output col).
__global__ __launch_bounds__(256) void filter_net_kernel(
    const float* __restrict__ ef, const float* __restrict__ W1,
    const float* __restrict__ b1, const float* __restrict__ W2,
    const float* __restrict__ b2, const float* __restrict__ input,
    unsigned* __restrict__ wq, float* __restrict__ wsc,
    unsigned* __restrict__ xq, float* __restrict__ xsc,
    float* __restrict__ zero_base, int nzero4, int n_nodes) {
  const int t = threadIdx.x;
  const int f0 = blockIdx.x * FN_FPB;

  for (int gid = blockIdx.x * 256 + t; gid < nzero4; gid += gridDim.x * 256)
    ((float4*)zero_base)[gid] = make_float4(0.f, 0.f, 0.f, 0.f);

  // x quantization: one node per thread (grid 65536 >= n_nodes).
  {
    const int gid = blockIdx.x * 256 + t;
    if (gid < n_nodes) {
      const float4* xr = (const float4*)(input + (size_t)gid * 16);
      const float4 v0 = xr[0], v1 = xr[1], v2 = xr[2], v3 = xr[3];
      float am = fabsf(v0.x);
      am = fmaxf(am, fabsf(v0.y)); am = fmaxf(am, fabsf(v0.z));
      am = fmaxf(am, fabsf(v0.w));
      am = fmaxf(am, fabsf(v1.x)); am = fmaxf(am, fabsf(v1.y));
      am = fmaxf(am, fabsf(v1.z)); am = fmaxf(am, fabsf(v1.w));
      am = fmaxf(am, fabsf(v2.x)); am = fmaxf(am, fabsf(v2.y));
      am = fmaxf(am, fabsf(v2.z)); am = fmaxf(am, fabsf(v2.w));
      am = fmaxf(am, fabsf(v3.x)); am = fmaxf(am, fabsf(v3.y));
      am = fmaxf(am, fabsf(v3.z)); am = fmaxf(am, fabsf(v3.w));
      const float inv = am > 0.f ? 127.f / am : 0.f;
      uint4 o;
      o.x = q8(v0.x, inv) | (q8(v0.y, inv) << 8) | (q8(v0.z, inv) << 16) |
            (q8(v0.w, inv) << 24);
      o.y = q8(v1.x, inv) | (q8(v1.y, inv) << 8) | (q8(v1.z, inv) << 16) |
            (q8(v1.w, inv) << 24);
      o.z = q8(v2.x, inv) | (q8(v2.y, inv) << 8) | (q8(v2.z, inv) << 16) |
            (q8(v2.w, inv) << 24);
      o.w = q8(v3.x, inv) | (q8(v3.y, inv) << 8) | (q8(v3.z, inv) << 16) |
            (q8(v3.w, inv) << 24);
      ((uint4*)xq)[gid] = o;
      xsc[gid] = am * (1.f / 127.f);
    }
  }

  __shared__ float ef_s[FN_FPB * EDGE_FEAT];   // 2 KB
  __shared__ float h_s[FN_FPB][HIDDEN];        // 8 KB
  ef_s[t] = ef[f0 * EDGE_FEAT + t];
  ef_s[t + 256] = ef[f0 * EDGE_FEAT + t + 256];
  __syncthreads();

  // stage 1: 2048 h values, 8 per thread.
  {
    const int hi = t & 127;
    const int fb = (t >> 7) * 8;
    float a[8];
    #pragma unroll
    for (int r = 0; r < 8; ++r) a[r] = b1[hi];
    for (int k0 = 0; k0 < EDGE_FEAT; k0 += 4) {
      float w1v[4];
      #pragma unroll
      for (int m = 0; m < 4; ++m) w1v[m] = W1[(k0 + m) * HIDDEN + hi];
      #pragma unroll
      for (int r = 0; r < 8; ++r) {
        const float4 e4 = *(const float4*)&ef_s[(fb + r) * EDGE_FEAT + k0];
        a[r] = fmaf(e4.x, w1v[0], a[r]);
        a[r] = fmaf(e4.y, w1v[1], a[r]);
        a[r] = fmaf(e4.z, w1v[2], a[r]);
        a[r] = fmaf(e4.w, w1v[3], a[r]);
      }
    }
    #pragma unroll
    for (int r = 0; r < 8; ++r) h_s[fb + r][hi] = a[r] > 0.f ? a[r] : 0.f;
  }
  __syncthreads();

  // stage 2: cq owns cols m=4cq..4cq+3 (m = i*16+o) for filters grp*4+q.
  const int cq = t & 63;
  const int grp = t >> 6;
  float4 facc[4];
  const float4 bb = *(const float4*)(b2 + 4 * cq);
  #pragma unroll
  for (int q = 0; q < 4; ++q) facc[q] = bb;
  for (int k0 = 0; k0 < HIDDEN; k0 += 4) {
    float4 w2v[4];
    #pragma unroll
    for (int m = 0; m < 4; ++m)
      w2v[m] = ((const float4*)(W2 + (size_t)(k0 + m) * WROW))[cq];
    #pragma unroll
    for (int q = 0; q < 4; ++q) {
      const float4 h4 = *(const float4*)&h_s[grp * 4 + q][k0];
      facc[q].x = fmaf(h4.x, w2v[0].x, facc[q].x);
      facc[q].y = fmaf(h4.x, w2v[0].y, facc[q].y);
      facc[q].z = fmaf(h4.x, w2v[0].z, facc[q].z);
      facc[q].w = fmaf(h4.x, w2v[0].w, facc[q].w);
      facc[q].x = fmaf(h4.y, w2v[1].x, facc[q].x);
      facc[q].y = fmaf(h4.y, w2v[1].y, facc[q].y);
      facc[q].z = fmaf(h4.y, w2v[1].z, facc[q].z);
      facc[q].w = fmaf(h4.y, w2v[1].w, facc[q].w);
      facc[q].x = fmaf(h4.z, w2v[2].x, facc[q].x);
      facc[q].y = fmaf(h4.z, w2v[2].y, facc[q].y);
      facc[q].z = fmaf(h4.z, w2v[2].z, facc[q].z);
      facc[q].w = fmaf(h4.z, w2v[2].w, facc[q].w);
      facc[q].x = fmaf(h4.w, w2v[3].x, facc[q].x);
      facc[q].y = fmaf(h4.w, w2v[3].y, facc[q].y);
      facc[q].z = fmaf(h4.w, w2v[3].z, facc[q].z);
      facc[q].w = fmaf(h4.w, w2v[3].w, facc[q].w);
    }
  }

  // int8 epilogue: per q, wave-allreduce rowmax -> quantize -> cross-lane
  // repack from m-order (lane cq = bytes 4cq..4cq+3) to (k,c)-order.
  const int k = cq >> 4;
  const int c = cq & 15;
  #pragma unroll
  for (int q = 0; q < 4; ++q) {
    float am = fmaxf(fmaxf(fabsf(facc[q].x), fabsf(facc[q].y)),
                     fmaxf(fabsf(facc[q].z), fabsf(facc[q].w)));
    #pragma unroll
    for (int off = 1; off < 64; off <<= 1)
      am = fmaxf(am, __shfl_xor(am, off));
    const float inv = am > 0.f ? 127.f / am : 0.f;
    const unsigned myq = q8(facc[q].x, inv) | (q8(facc[q].y, inv) << 8) |
                         (q8(facc[q].z, inv) << 16) |
                         (q8(facc[q].w, inv) << 24);
    unsigned out = 0;
    #pragma unroll
    for (int kk = 0; kk < 4; ++kk) {
      const unsigned sd =
          (unsigned)__shfl((int)myq, (4 * k + kk) * 4 + (c >> 2));
      out |= ((sd >> (8 * (c & 3))) & 0xFF) << (8 * kk);
    }
    const int f = f0 + grp * 4 + q;
    wq[(size_t)f * 64 + cq] = out;
    if (cq == 0) wsc[f] = am * (1.f / 127.f);
  }
}

// ---------------- Kernel 2: edge kernel r23 — int8 gather (r15 structure) ---
// Structure byte-identical to r15 (the proven 51.5 µs scheduling); only the
// payload changed: 4x16B int8 weight loads (256 B/row), whole-x uint4 load
// (no DPP broadcast needed), scales, and sdot4 inner product.
template <int CTRL, int OLD>
__device__ __forceinline__ int dpp_i(int v) {
  return __builtin_amdgcn_update_dpp(OLD, v, CTRL, 0xf, 0xf, false);
}
template <int CTRL>
__device__ __forceinline__ float dpp_f(float v) {
  return __builtin_bit_cast(
      float, __builtin_amdgcn_update_dpp(0, __builtin_bit_cast(int, v), CTRL,
                                         0xf, 0xf, false));
}

template <int CTRL>
__device__ __forceinline__ void seg_step_dpp(int sl, fvec4& acc) {
  const int os = dpp_i<CTRL, -1>(sl);
  const float ox = dpp_f<CTRL>(acc.x);
  const float oy = dpp_f<CTRL>(acc.y);
  const float oz = dpp_f<CTRL>(acc.z);
  const float ow = dpp_f<CTRL>(acc.w);
  if (os == sl) {
    acc.x += ox; acc.y += oy; acc.z += oz; acc.w += ow;
  }
}

__global__ __launch_bounds__(256) void edge_kernel(
    const unsigned* __restrict__ xq, const float* __restrict__ xsc,
    const unsigned* __restrict__ wq, const float* __restrict__ wsc,
    const int* __restrict__ idxn, const int* __restrict__ idxe,
    const int* __restrict__ seg, float* __restrict__ sums,
    float* __restrict__ deg, int n_edges) {
  __shared__ float lds_acc[4][WSLOTS * LSTR];   // 4 x 4 KB (wave-private)
  __shared__ int lds_map[4][WSLOTS];

  const int t = threadIdx.x;
  const int lane = t & 63;
  const int w = t >> 6;
  const int e16 = lane >> 2;
  const int j = lane & 3;
  float* __restrict__ acc_w = lds_acc[w];

  const long wv_base = (long)blockIdx.x * 256 + w * 64;
  long rem = n_edges - wv_base;
  const int valid_cnt = rem < 0 ? 0 : (rem > 64 ? 64 : (int)rem);

  long el = wv_base + lane;
  const bool vl = el < n_edges;
  if (!vl) el = n_edges - 1;
  const int s_l = seg[el];
  const int n_l = idxn[el];
  const int f_l = idxe[el];
  const int sv = vl ? s_l : -1;

  const int sprev = __shfl(sv, (lane - 1) & 63);
  const bool head = vl && (lane == 0 || sprev != sv);
  const unsigned long long bal = __ballot(head);
  const int r = (int)__popcll(bal & ((1ull << lane) - 1ull));
  const int r_w = (int)__popcll(bal);

  for (int idx = lane; idx < r_w * LSTR; idx += 64) acc_w[idx] = 0.f;

  const int slot_l = r - (head ? 0 : 1);
  if (head) lds_map[w][slot_l] = (lane << 20) | sv;   // head lane | node id

  // 4 phases of 16 edges; relaxed scheduling (compiler interleave proven
  // best across r9..r22's pinned-pipeline attempts).
  #pragma unroll
  for (int g = 0; g < 4; ++g) {
    const int src = g * 16 + e16;
    const int fg = __shfl(f_l, src);
    const int ng = __shfl(n_l, src);
    const int sl = __shfl(slot_l, src);
    const bool ve = src < valid_cnt;

    // weight row: 64 dwords, dword p=k*16+c. Lane j instr k reads uvec4 at
    // dword k*16+4j (lanes j=0..3 contiguous 64 B -> one line per edge).
    const uvec4* wrow = (const uvec4*)(wq + ((size_t)fg << 6));
    uvec4 wv[4];
    #pragma unroll
    for (int k = 0; k < 4; ++k) wv[k] = wrow[k * 4 + j];

    const uvec4 xv = *(const uvec4*)(xq + ((size_t)ng << 2));
    const float sxw = xsc[ng] * wsc[fg];

    int a0 = 0, a1 = 0, a2 = 0, a3 = 0;
    #pragma unroll
    for (int k = 0; k < 4; ++k) {
      a0 = dot4i8(xv[k], wv[k].x, a0);
      a1 = dot4i8(xv[k], wv[k].y, a1);
      a2 = dot4i8(xv[k], wv[k].z, a2);
      a3 = dot4i8(xv[k], wv[k].w, a3);
    }
    fvec4 acc;
    acc.x = (float)a0 * sxw;
    acc.y = (float)a1 * sxw;
    acc.z = (float)a2 * sxw;
    acc.w = (float)a3 * sxw;
    if (!ve) { acc.x = 0.f; acc.y = 0.f; acc.z = 0.f; acc.w = 0.f; }

    seg_step_dpp<0x104>(sl, acc);            // + next edge (within row)
    seg_step_dpp<0x108>(sl, acc);            // + edges +2,+3
    const int pslot = dpp_i<0x114, -1>(sl);  // prev edge's slot
    if (ve && pslot != sl) {                 // sub-run head -> LDS accumulate
      float* p = acc_w + sl * LSTR + j * 4;
      atomicAdd(p + 0, acc.x);
      atomicAdd(p + 1, acc.y);
      atomicAdd(p + 2, acc.z);
      atomicAdd(p + 3, acc.w);
    }
  }

  // drain wave-local DS before reading slots (no barrier: wave-private).
  asm volatile("s_waitcnt lgkmcnt(0)" ::: "memory");

  // flush; deg derived from head-lane deltas (no cnt accumulation).
  const int ch = lane & 15;
  for (int slot = lane >> 4; slot < r_w; slot += 4) {
    const int m0 = lds_map[w][slot];
    const int node = m0 & 0xFFFFF;
    atomicAdd(sums + ((size_t)node << 4) + ch, acc_w[slot * LSTR + ch]);
    if (ch == 0) {
      const int start = m0 >> 20;
      const int end =
          (slot + 1 < r_w) ? (lds_map[w][slot + 1] >> 20) : valid_cnt;
      atomicAdd(deg + node, (float)(end - start));
    }
  }
}

// ---------------- Kernel 3: divide by degree --------------------------------
__global__ __launch_bounds__(256) void finalize_kernel(
    const float* __restrict__ sums, const float* __restrict__ deg,
    float* __restrict__ out, int n_nodes) {
  const int n = blockIdx.x * blockDim.x + threadIdx.x;
  if (n >= n_nodes) return;
  const float d = deg[n];
  const float scale = d > 0.f ? 1.f / d : 0.f;
  const float4* sp = (const float4*)(sums + (size_t)n * OUT_CH);
  float4* op = (float4*)(out + (size_t)n * OUT_CH);
  #pragma unroll
  for (int q = 0; q < 4; ++q) {
    float4 v = sp[q];
    v.x *= scale; v.y *= scale; v.z *= scale; v.w *= scale;
    op[q] = v;
  }
}

extern "C" void kernel_launch(void* const* d_in, const int* in_sizes, int n_in,
                              void* d_out, int out_size, void* d_ws, size_t ws_size,
                              hipStream_t stream) {
  const float* input = (const float*)d_in[0];
  const int* idxn    = (const int*)d_in[1];
  const int* idxe    = (const int*)d_in[2];
  const int* seg     = (const int*)d_in[3];
  const float* ef    = (const float*)d_in[4];
  const float* W1    = (const float*)d_in[5];
  const float* b1    = (const float*)d_in[6];
  const float* W2    = (const float*)d_in[7];
  const float* b2    = (const float*)d_in[8];
  float* out = (float*)d_out;

  const int n_nodes   = in_sizes[0] / IN_CH;
  const int n_edges   = in_sizes[1];
  const int n_filters = in_sizes[4] / EDGE_FEAT;

  // workspace: wq [F*64 u32] (1MB) | wsc [F f32] | xq [N*4 u32] | xsc [N f32]
  //            | sums [N*16 f32] | deg [N f32]
  unsigned* wq = (unsigned*)d_ws;
  float* wsc = (float*)(wq + (size_t)n_filters * 64);
  unsigned* xq = (unsigned*)(wsc + n_filters);
  float* xsc = (float*)(xq + (size_t)n_nodes * 4);
  float* sums = xsc + n_nodes;
  float* deg  = sums + (size_t)n_nodes * OUT_CH;

  const int nzero4 = (n_nodes * (OUT_CH + 1)) / 4;
  filter_net_kernel<<<n_filters / FN_FPB, 256, 0, stream>>>(
      ef, W1, b1, W2, b2, input, wq, wsc, xq, xsc, sums, nzero4, n_nodes);

  const long n_blocks = ((long)n_edges + 255) / 256;
  edge_kernel<<<(int)n_blocks, 256, 0, stream>>>(
      xq, xsc, wq, wsc, idxn, idxe, seg, sums, deg, n_edges);

  finalize_kernel<<<(n_nodes + 255) / 256, 256, 0, stream>>>(sums, deg, out,
                                                             n_nodes);
}